// Round 4
// baseline (340.967 us; speedup 1.0000x reference)
//
#include <hip/hip_runtime.h>

typedef __bf16 bf16x8 __attribute__((ext_vector_type(8)));
typedef float f32x4 __attribute__((ext_vector_type(4)));

#define D_MODEL 768
#define NH 12
#define DKH 64
#define BATCH 4
#define SEQ 2048
#define ROWS (BATCH*SEQ)   /* 8192 */
#define N_QKV (3*D_MODEL)  /* 2304 */
#define QSCALE 0.18033688f /* 0.125 * log2(e): folds softmax scale + exp2 domain into Q */

// ---------------- convert fp32 -> bf16 ----------------
__global__ void k_convert(const float* __restrict__ in, __bf16* __restrict__ out, int n) {
  int i = (blockIdx.x * blockDim.x + threadIdx.x) * 4;
  if (i >= n) return;
  float4 v = *(const float4*)(in + i);
  out[i+0] = (__bf16)v.x; out[i+1] = (__bf16)v.y;
  out[i+2] = (__bf16)v.z; out[i+3] = (__bf16)v.w;
}

// ---------------- transpose fp32 [R][C] -> bf16 [C][R] ----------------
__global__ void k_transpose(const float* __restrict__ in, __bf16* __restrict__ out, int R, int C) {
  __shared__ float tile[32][33];
  int c0 = blockIdx.x * 32, r0 = blockIdx.y * 32;
  int tx = threadIdx.x, ty = threadIdx.y;   // (32, 8)
  #pragma unroll
  for (int i = 0; i < 4; ++i) {
    int r = ty + i*8;
    tile[r][tx] = in[(size_t)(r0 + r)*C + c0 + tx];
  }
  __syncthreads();
  #pragma unroll
  for (int i = 0; i < 4; ++i) {
    int c = ty + i*8;
    out[(size_t)(c0 + c)*R + r0 + tx] = (__bf16)tile[tx][c];
  }
}

// ---------------- GEMM core: 2-phase double-buffered 128x128 tile ----------------
__device__ __forceinline__ void gemm_stage(const __bf16* __restrict__ A, int lda,
                                           const __bf16* __restrict__ Bt, int ldb,
                                           int m0, int n0, int kt,
                                           __bf16* lA, __bf16* lB) {
  const int tid  = threadIdx.x;
  const int lane = tid & 63;
  const int wid  = tid >> 6;
  #pragma unroll
  for (int c = 0; c < 2; ++c) {
    int chunk = wid*2 + c;               // 0..7
    int bo = chunk*1024 + lane*16;       // byte offset in tile
    int m  = bo >> 6;                    // 64B per row
    int kb = (bo & 63) >> 1;             // element in row
    __builtin_amdgcn_global_load_lds(
      (const __attribute__((address_space(1))) void*)(A + (size_t)(m0 + m)*lda + kt + kb),
      (__attribute__((address_space(3))) void*)(lA + chunk*512), 16, 0, 0);
    __builtin_amdgcn_global_load_lds(
      (const __attribute__((address_space(1))) void*)(Bt + (size_t)(n0 + m)*ldb + kt + kb),
      (__attribute__((address_space(3))) void*)(lB + chunk*512), 16, 0, 0);
  }
}

__device__ __forceinline__ void gemm_core(const __bf16* __restrict__ A, int lda,
                                          const __bf16* __restrict__ Bt, int ldb,
                                          int K, int m0, int n0,
                                          __bf16* lA, __bf16* lB, f32x4 acc[4][4]) {
  const int lane = threadIdx.x & 63;
  const int wid  = threadIdx.x >> 6;
  const int wm   = (wid >> 1) * 64;
  const int wn   = (wid & 1) * 64;
  const int lr   = lane & 15;
  const int lk   = lane >> 4;

  gemm_stage(A, lda, Bt, ldb, m0, n0, 0, lA, lB);
  __syncthreads();
  int cur = 0;
  for (int kt = 0; kt < K; kt += 32) {
    if (kt + 32 < K)
      gemm_stage(A, lda, Bt, ldb, m0, n0, kt + 32, lA + (cur^1)*4096, lB + (cur^1)*4096);
    const __bf16* cA = lA + cur*4096;
    const __bf16* cB = lB + cur*4096;
    bf16x8 af[4], bfr[4];
    #pragma unroll
    for (int i = 0; i < 4; ++i) {
      af[i]  = *(const bf16x8*)(cA + (wm + i*16 + lr)*32 + lk*8);
      bfr[i] = *(const bf16x8*)(cB + (wn + i*16 + lr)*32 + lk*8);
    }
    #pragma unroll
    for (int mi = 0; mi < 4; ++mi)
      #pragma unroll
      for (int ni = 0; ni < 4; ++ni)
        acc[mi][ni] = __builtin_amdgcn_mfma_f32_16x16x32_bf16(af[mi], bfr[ni], acc[mi][ni], 0, 0, 0);
    __syncthreads();
    cur ^= 1;
  }
}

// ---------------- GEMM1: qkv = xb @ WqkvT + bqkv, scatter to Q(scaled),K,V^T ----------------
__global__ __launch_bounds__(256) void k_gemm_qkv(const __bf16* __restrict__ xb,
                                                  const __bf16* __restrict__ wT,
                                                  const float* __restrict__ bias,
                                                  __bf16* __restrict__ qb,
                                                  __bf16* __restrict__ kb,
                                                  __bf16* __restrict__ vtb) {
  __shared__ __align__(16) __bf16 lA[2*128*32];
  __shared__ __align__(16) __bf16 lB[2*128*32];
  f32x4 acc[4][4];
  #pragma unroll
  for (int i = 0; i < 4; ++i)
    #pragma unroll
    for (int j = 0; j < 4; ++j) { f32x4 z = {0.f,0.f,0.f,0.f}; acc[i][j] = z; }

  const int m0 = blockIdx.y * 128, n0 = blockIdx.x * 128;
  gemm_core(xb, D_MODEL, wT, D_MODEL, D_MODEL, m0, n0, lA, lB, acc);

  const int lane = threadIdx.x & 63;
  const int wid  = threadIdx.x >> 6;
  const int wm = (wid >> 1) * 64, wn = (wid & 1) * 64;
  const int lr = lane & 15, lk = lane >> 4;
  #pragma unroll
  for (int mi = 0; mi < 4; ++mi) {
    #pragma unroll
    for (int ni = 0; ni < 4; ++ni) {
      int col = n0 + wn + ni*16 + lr;
      int t   = col / D_MODEL;
      int r2  = col - t*D_MODEL;
      int hh  = r2 >> 6, dk = r2 & 63;
      float bv = bias[col];
      #pragma unroll
      for (int j = 0; j < 4; ++j) {
        int row = m0 + wm + mi*16 + lk*4 + j;
        int bb = row >> 11, ss = row & 2047;
        float fv = acc[mi][ni][j] + bv;
        if (t == 0)      qb [(((size_t)bb*NH + hh)*SEQ + ss)*DKH + dk] = (__bf16)(fv * QSCALE);
        else if (t == 1) kb [(((size_t)bb*NH + hh)*SEQ + ss)*DKH + dk] = (__bf16)fv;
        else             vtb[(((size_t)bb*NH + hh)*DKH + dk)*SEQ + ss] = (__bf16)fv;
      }
    }
  }
}

// ---------------- GEMM3: out = attn @ WoutT + bout (fp32 out) ----------------
__global__ __launch_bounds__(256) void k_gemm_out(const __bf16* __restrict__ ab,
                                                  const __bf16* __restrict__ wT,
                                                  const float* __restrict__ bias,
                                                  float* __restrict__ out) {
  __shared__ __align__(16) __bf16 lA[2*128*32];
  __shared__ __align__(16) __bf16 lB[2*128*32];
  f32x4 acc[4][4];
  #pragma unroll
  for (int i = 0; i < 4; ++i)
    #pragma unroll
    for (int j = 0; j < 4; ++j) { f32x4 z = {0.f,0.f,0.f,0.f}; acc[i][j] = z; }

  const int m0 = blockIdx.y * 128, n0 = blockIdx.x * 128;
  gemm_core(ab, D_MODEL, wT, D_MODEL, D_MODEL, m0, n0, lA, lB, acc);

  const int lane = threadIdx.x & 63;
  const int wid  = threadIdx.x >> 6;
  const int wm = (wid >> 1) * 64, wn = (wid & 1) * 64;
  const int lr = lane & 15, lk = lane >> 4;
  #pragma unroll
  for (int mi = 0; mi < 4; ++mi) {
    #pragma unroll
    for (int ni = 0; ni < 4; ++ni) {
      int col = n0 + wn + ni*16 + lr;
      float bv = bias[col];
      #pragma unroll
      for (int j = 0; j < 4; ++j) {
        int row = m0 + wm + mi*16 + lk*4 + j;
        out[(size_t)row*D_MODEL + col] = acc[mi][ni][j] + bv;
      }
    }
  }
}

// ---------------- Flash attention (causal), barrier-free, LPT-ordered ----------------
// 1D grid 768 blocks: qi = 15 - bid/48 (heaviest blocks dispatch FIRST -> no tail),
// bh = bid % 48. Block covers q-rows [qi*128, qi*128+128), wave wid owns 32 rows.
// K/V are L2-resident (256KB/head) -> read fragments DIRECT from global, no LDS
// staging, no __syncthreads; waves run independently and exit when causally done.
// Q pre-scaled by 0.125*log2e at GEMM1 -> softmax in exp2 domain.
__global__ __launch_bounds__(256, 4) void k_attn(const __bf16* __restrict__ q,
                                                 const __bf16* __restrict__ k,
                                                 const __bf16* __restrict__ vt,
                                                 __bf16* __restrict__ out) {
  __shared__ __align__(16) char lsP[4][4096];   // per-wave P [32 q][64 kv] bf16, swizzled

  const int tid  = threadIdx.x;
  const int lane = tid & 63;
  const int wid  = tid >> 6;
  const int lr   = lane & 15;
  const int lk   = lane >> 4;

  const int bid = blockIdx.x;
  const int qi  = 15 - bid / (BATCH*NH);   // heavy (qi=15) first
  const int bh  = bid % (BATCH*NH);
  const int b   = bh / NH, h = bh - b*NH;
  const int q0w = qi*128 + wid*32;

  const __bf16* qh = q  + (size_t)bh*SEQ*DKH;
  const __bf16* kh = k  + (size_t)bh*SEQ*DKH;
  const __bf16* vh = vt + (size_t)bh*DKH*SEQ;
  char* pw = lsP[wid];

  bf16x8 aq[2][2];
  #pragma unroll
  for (int r = 0; r < 2; ++r)
    #pragma unroll
    for (int kh2 = 0; kh2 < 2; ++kh2)
      aq[r][kh2] = *(const bf16x8*)(qh + (size_t)(q0w + r*16 + lr)*DKH + kh2*32 + lk*8);

  f32x4 o[2][4];
  #pragma unroll
  for (int r = 0; r < 2; ++r)
    #pragma unroll
    for (int df = 0; df < 4; ++df) { f32x4 z = {0.f,0.f,0.f,0.f}; o[r][df] = z; }
  float m_i[2][4], l_ln[2][4];      // per-lane partial row sum (deferred reduce)
  #pragma unroll
  for (int r = 0; r < 2; ++r)
    #pragma unroll
    for (int j = 0; j < 4; ++j) { m_i[r][j] = -1e30f; l_ln[r][j] = 0.f; }

  const int nt = (q0w + 95) >> 6;   // per-wave causal tile count

  for (int t = 0; t < nt; ++t) {
    const int kv0 = t * 64;
    // ---- S = Q K^T : [32 q][64 kv], K direct from global (L2) ----
    f32x4 sc[2][4];
    #pragma unroll
    for (int r = 0; r < 2; ++r)
      #pragma unroll
      for (int n = 0; n < 4; ++n) { f32x4 z = {0.f,0.f,0.f,0.f}; sc[r][n] = z; }
    #pragma unroll
    for (int n = 0; n < 4; ++n) {
      const __bf16* kr = kh + (size_t)(kv0 + n*16 + lr)*DKH;
      bf16x8 bk0 = *(const bf16x8*)(kr + lk*8);
      bf16x8 bk1 = *(const bf16x8*)(kr + 32 + lk*8);
      #pragma unroll
      for (int r = 0; r < 2; ++r) {
        sc[r][n] = __builtin_amdgcn_mfma_f32_16x16x32_bf16(aq[r][0], bk0, sc[r][n], 0, 0, 0);
        sc[r][n] = __builtin_amdgcn_mfma_f32_16x16x32_bf16(aq[r][1], bk1, sc[r][n], 0, 0, 0);
      }
    }
    // ---- causal mask (diag tiles only) ----
    if (kv0 + 63 > q0w) {
      #pragma unroll
      for (int r = 0; r < 2; ++r)
        #pragma unroll
        for (int n = 0; n < 4; ++n) {
          int kv = kv0 + n*16 + lr;
          #pragma unroll
          for (int j = 0; j < 4; ++j)
            if (kv > q0w + r*16 + lk*4 + j) sc[r][n][j] = -1e30f;
        }
    }
    // ---- row max ----
    float pm[2][4];
    #pragma unroll
    for (int r = 0; r < 2; ++r)
      #pragma unroll
      for (int j = 0; j < 4; ++j) {
        float v = fmaxf(fmaxf(sc[r][0][j], sc[r][1][j]), fmaxf(sc[r][2][j], sc[r][3][j]));
        #pragma unroll
        for (int msk = 1; msk <= 8; msk <<= 1)
          v = fmaxf(v, __shfl_xor(v, msk));
        pm[r][j] = v;
      }
    // ---- defer-max (T13): rescale only when max grew past threshold ----
    bool need = false;
    #pragma unroll
    for (int r = 0; r < 2; ++r)
      #pragma unroll
      for (int j = 0; j < 4; ++j)
        need = need || (pm[r][j] > m_i[r][j] + 8.0f);
    if (__any(need)) {
      #pragma unroll
      for (int r = 0; r < 2; ++r)
        #pragma unroll
        for (int j = 0; j < 4; ++j) {
          float mn = fmaxf(m_i[r][j], pm[r][j]);
          float alpha = exp2f(m_i[r][j] - mn);
          m_i[r][j] = mn;
          l_ln[r][j] *= alpha;
          #pragma unroll
          for (int df = 0; df < 4; ++df) o[r][df][j] *= alpha;
        }
    }
    // ---- P = exp2(s - m) -> bf16 -> LDS (swizzled); per-lane l partial ----
    #pragma unroll
    for (int r = 0; r < 2; ++r)
      #pragma unroll
      for (int n = 0; n < 4; ++n)
        #pragma unroll
        for (int j = 0; j < 4; ++j) {
          int row = r*16 + lk*4 + j;
          __bf16 pb = (__bf16)exp2f(sc[r][n][j] - m_i[r][j]);
          l_ln[r][j] += (float)pb;
          *(__bf16*)(pw + row*128 + ((2*(n*16 + lr)) ^ ((row & 7) << 4))) = pb;
        }
    // ---- O += P V, V direct from global (L2) ----
    bf16x8 pa[2][2];
    #pragma unroll
    for (int r = 0; r < 2; ++r) {
      int row = r*16 + lr;
      int sw = (row & 7) << 4;
      #pragma unroll
      for (int kh2 = 0; kh2 < 2; ++kh2)
        pa[r][kh2] = *(const bf16x8*)(pw + row*128 + ((kh2*64 + lk*16) ^ sw));
    }
    #pragma unroll
    for (int df = 0; df < 4; ++df) {
      const __bf16* vr = vh + (size_t)(df*16 + lr)*SEQ + kv0;
      bf16x8 bv0 = *(const bf16x8*)(vr + lk*8);
      bf16x8 bv1 = *(const bf16x8*)(vr + 32 + lk*8);
      #pragma unroll
      for (int r = 0; r < 2; ++r) {
        o[r][df] = __builtin_amdgcn_mfma_f32_16x16x32_bf16(pa[r][0], bv0, o[r][df], 0, 0, 0);
        o[r][df] = __builtin_amdgcn_mfma_f32_16x16x32_bf16(pa[r][1], bv1, o[r][df], 0, 0, 0);
      }
    }
  }

  // ---- epilogue: reduce l across the 16-lane group (deferred), O/l, store ----
  float inv[2][4];
  #pragma unroll
  for (int r = 0; r < 2; ++r)
    #pragma unroll
    for (int j = 0; j < 4; ++j) {
      float v = l_ln[r][j];
      #pragma unroll
      for (int msk = 1; msk <= 8; msk <<= 1) v += __shfl_xor(v, msk);
      inv[r][j] = 1.0f / v;
    }
  #pragma unroll
  for (int r = 0; r < 2; ++r)
    #pragma unroll
    for (int df = 0; df < 4; ++df) {
      int d = df*16 + lr;
      #pragma unroll
      for (int j = 0; j < 4; ++j) {
        int ss = q0w + r*16 + lk*4 + j;
        out[((size_t)b*SEQ + ss)*D_MODEL + h*DKH + d] = (__bf16)(o[r][df][j] * inv[r][j]);
      }
    }
}

// ---------------- launch ----------------
extern "C" void kernel_launch(void* const* d_in, const int* in_sizes, int n_in,
                              void* d_out, int out_size, void* d_ws, size_t ws_size,
                              hipStream_t stream) {
  const float* x    = (const float*)d_in[0];
  /* d_in[1] = causal mask, implemented analytically */
  const float* Wqkv = (const float*)d_in[2];
  const float* bqkv = (const float*)d_in[3];
  const float* Wout = (const float*)d_in[4];
  const float* bout = (const float*)d_in[5];
  float* out = (float*)d_out;

  char* w = (char*)d_ws;
  __bf16* xb    = (__bf16*)w; w += (size_t)ROWS*D_MODEL*2;
  __bf16* wqkvT = (__bf16*)w; w += (size_t)N_QKV*D_MODEL*2;
  __bf16* woutT = (__bf16*)w; w += (size_t)D_MODEL*D_MODEL*2;
  __bf16* qb    = (__bf16*)w; w += (size_t)BATCH*NH*SEQ*DKH*2;
  __bf16* kb    = (__bf16*)w; w += (size_t)BATCH*NH*SEQ*DKH*2;
  __bf16* vtb   = (__bf16*)w; w += (size_t)BATCH*NH*SEQ*DKH*2;
  __bf16* attnb = (__bf16*)w; w += (size_t)ROWS*D_MODEL*2;

  k_convert<<<(ROWS*D_MODEL/4 + 255)/256, 256, 0, stream>>>(x, xb, ROWS*D_MODEL);
  k_transpose<<<dim3(N_QKV/32, D_MODEL/32), dim3(32, 8), 0, stream>>>(Wqkv, wqkvT, D_MODEL, N_QKV);
  k_transpose<<<dim3(D_MODEL/32, D_MODEL/32), dim3(32, 8), 0, stream>>>(Wout, woutT, D_MODEL, D_MODEL);
  k_gemm_qkv<<<dim3(N_QKV/128, ROWS/128), 256, 0, stream>>>(xb, wqkvT, bqkv, qb, kb, vtb);
  k_attn<<<768, 256, 0, stream>>>(qb, kb, vtb, attnb);
  k_gemm_out<<<dim3(D_MODEL/128, ROWS/128), 256, 0, stream>>>(attnb, woutT, bout, out);
}

// Round 5
// 197.794 us; speedup vs baseline: 1.7238x; 1.7238x over previous
//
#include <hip/hip_runtime.h>

typedef __bf16 bf16x8 __attribute__((ext_vector_type(8)));
typedef __bf16 bf16x4 __attribute__((ext_vector_type(4)));
typedef float f32x4 __attribute__((ext_vector_type(4)));

#define D_MODEL 768
#define NH 12
#define DKH 64
#define BATCH 4
#define SEQ 2048
#define ROWS (BATCH*SEQ)   /* 8192 */
#define N_QKV (3*D_MODEL)  /* 2304 */
#define QSCALE 0.18033688f /* 0.125 * log2(e): folds softmax scale + exp2 domain into Q */

// ---------------- convert fp32 -> bf16 ----------------
__global__ void k_convert(const float* __restrict__ in, __bf16* __restrict__ out, int n) {
  int i = (blockIdx.x * blockDim.x + threadIdx.x) * 4;
  if (i >= n) return;
  float4 v = *(const float4*)(in + i);
  out[i+0] = (__bf16)v.x; out[i+1] = (__bf16)v.y;
  out[i+2] = (__bf16)v.z; out[i+3] = (__bf16)v.w;
}

// ---------------- transpose fp32 [R][C] -> bf16 [C][R] ----------------
__global__ void k_transpose(const float* __restrict__ in, __bf16* __restrict__ out, int R, int C) {
  __shared__ float tile[32][33];
  int c0 = blockIdx.x * 32, r0 = blockIdx.y * 32;
  int tx = threadIdx.x, ty = threadIdx.y;   // (32, 8)
  #pragma unroll
  for (int i = 0; i < 4; ++i) {
    int r = ty + i*8;
    tile[r][tx] = in[(size_t)(r0 + r)*C + c0 + tx];
  }
  __syncthreads();
  #pragma unroll
  for (int i = 0; i < 4; ++i) {
    int c = ty + i*8;
    out[(size_t)(c0 + c)*R + r0 + tx] = (__bf16)tile[tx][c];
  }
}

// ---------------- GEMM core: 2-phase double-buffered 128x128 tile ----------------
__device__ __forceinline__ void gemm_stage(const __bf16* __restrict__ A, int lda,
                                           const __bf16* __restrict__ Bt, int ldb,
                                           int m0, int n0, int kt,
                                           __bf16* lA, __bf16* lB) {
  const int tid  = threadIdx.x;
  const int lane = tid & 63;
  const int wid  = tid >> 6;
  #pragma unroll
  for (int c = 0; c < 2; ++c) {
    int chunk = wid*2 + c;               // 0..7
    int bo = chunk*1024 + lane*16;       // byte offset in tile
    int m  = bo >> 6;                    // 64B per row
    int kb = (bo & 63) >> 1;             // element in row
    __builtin_amdgcn_global_load_lds(
      (const __attribute__((address_space(1))) void*)(A + (size_t)(m0 + m)*lda + kt + kb),
      (__attribute__((address_space(3))) void*)(lA + chunk*512), 16, 0, 0);
    __builtin_amdgcn_global_load_lds(
      (const __attribute__((address_space(1))) void*)(Bt + (size_t)(n0 + m)*ldb + kt + kb),
      (__attribute__((address_space(3))) void*)(lB + chunk*512), 16, 0, 0);
  }
}

__device__ __forceinline__ void gemm_core(const __bf16* __restrict__ A, int lda,
                                          const __bf16* __restrict__ Bt, int ldb,
                                          int K, int m0, int n0,
                                          __bf16* lA, __bf16* lB, f32x4 acc[4][4]) {
  const int lane = threadIdx.x & 63;
  const int wid  = threadIdx.x >> 6;
  const int wm   = (wid >> 1) * 64;
  const int wn   = (wid & 1) * 64;
  const int lr   = lane & 15;
  const int lk   = lane >> 4;

  gemm_stage(A, lda, Bt, ldb, m0, n0, 0, lA, lB);
  __syncthreads();
  int cur = 0;
  for (int kt = 0; kt < K; kt += 32) {
    if (kt + 32 < K)
      gemm_stage(A, lda, Bt, ldb, m0, n0, kt + 32, lA + (cur^1)*4096, lB + (cur^1)*4096);
    const __bf16* cA = lA + cur*4096;
    const __bf16* cB = lB + cur*4096;
    bf16x8 af[4], bfr[4];
    #pragma unroll
    for (int i = 0; i < 4; ++i) {
      af[i]  = *(const bf16x8*)(cA + (wm + i*16 + lr)*32 + lk*8);
      bfr[i] = *(const bf16x8*)(cB + (wn + i*16 + lr)*32 + lk*8);
    }
    #pragma unroll
    for (int mi = 0; mi < 4; ++mi)
      #pragma unroll
      for (int ni = 0; ni < 4; ++ni)
        acc[mi][ni] = __builtin_amdgcn_mfma_f32_16x16x32_bf16(af[mi], bfr[ni], acc[mi][ni], 0, 0, 0);
    __syncthreads();
    cur ^= 1;
  }
}

// ---------------- GEMM1: qkv = xb @ WqkvT + bqkv, scatter to Q(scaled),K,V^T ----------------
__global__ __launch_bounds__(256) void k_gemm_qkv(const __bf16* __restrict__ xb,
                                                  const __bf16* __restrict__ wT,
                                                  const float* __restrict__ bias,
                                                  __bf16* __restrict__ qb,
                                                  __bf16* __restrict__ kb,
                                                  __bf16* __restrict__ vtb) {
  __shared__ __align__(16) __bf16 lA[2*128*32];
  __shared__ __align__(16) __bf16 lB[2*128*32];
  f32x4 acc[4][4];
  #pragma unroll
  for (int i = 0; i < 4; ++i)
    #pragma unroll
    for (int j = 0; j < 4; ++j) { f32x4 z = {0.f,0.f,0.f,0.f}; acc[i][j] = z; }

  const int m0 = blockIdx.y * 128, n0 = blockIdx.x * 128;
  gemm_core(xb, D_MODEL, wT, D_MODEL, D_MODEL, m0, n0, lA, lB, acc);

  const int lane = threadIdx.x & 63;
  const int wid  = threadIdx.x >> 6;
  const int wm = (wid >> 1) * 64, wn = (wid & 1) * 64;
  const int lr = lane & 15, lk = lane >> 4;
  #pragma unroll
  for (int mi = 0; mi < 4; ++mi) {
    #pragma unroll
    for (int ni = 0; ni < 4; ++ni) {
      int col = n0 + wn + ni*16 + lr;
      int t   = col / D_MODEL;
      int r2  = col - t*D_MODEL;
      int hh  = r2 >> 6, dk = r2 & 63;
      float bv = bias[col];
      #pragma unroll
      for (int j = 0; j < 4; ++j) {
        int row = m0 + wm + mi*16 + lk*4 + j;
        int bb = row >> 11, ss = row & 2047;
        float fv = acc[mi][ni][j] + bv;
        if (t == 0)      qb [(((size_t)bb*NH + hh)*SEQ + ss)*DKH + dk] = (__bf16)(fv * QSCALE);
        else if (t == 1) kb [(((size_t)bb*NH + hh)*SEQ + ss)*DKH + dk] = (__bf16)fv;
        else             vtb[(((size_t)bb*NH + hh)*DKH + dk)*SEQ + ss] = (__bf16)fv;
      }
    }
  }
}

// ---------------- GEMM3: out = attn @ WoutT + bout (fp32 out) ----------------
__global__ __launch_bounds__(256) void k_gemm_out(const __bf16* __restrict__ ab,
                                                  const __bf16* __restrict__ wT,
                                                  const float* __restrict__ bias,
                                                  float* __restrict__ out) {
  __shared__ __align__(16) __bf16 lA[2*128*32];
  __shared__ __align__(16) __bf16 lB[2*128*32];
  f32x4 acc[4][4];
  #pragma unroll
  for (int i = 0; i < 4; ++i)
    #pragma unroll
    for (int j = 0; j < 4; ++j) { f32x4 z = {0.f,0.f,0.f,0.f}; acc[i][j] = z; }

  const int m0 = blockIdx.y * 128, n0 = blockIdx.x * 128;
  gemm_core(ab, D_MODEL, wT, D_MODEL, D_MODEL, m0, n0, lA, lB, acc);

  const int lane = threadIdx.x & 63;
  const int wid  = threadIdx.x >> 6;
  const int wm = (wid >> 1) * 64, wn = (wid & 1) * 64;
  const int lr = lane & 15, lk = lane >> 4;
  #pragma unroll
  for (int mi = 0; mi < 4; ++mi) {
    #pragma unroll
    for (int ni = 0; ni < 4; ++ni) {
      int col = n0 + wn + ni*16 + lr;
      float bv = bias[col];
      #pragma unroll
      for (int j = 0; j < 4; ++j) {
        int row = m0 + wm + mi*16 + lk*4 + j;
        out[(size_t)row*D_MODEL + col] = acc[mi][ni][j] + bv;
      }
    }
  }
}

// ---------------- Flash attention (causal), swapped-QK in-register softmax ----------------
// R2 structure: grid (16, 48), 4 waves x 32 q-rows, KVBLK=64, K/V^T LDS dbuf (swizzled).
// QK^T computed SWAPPED: mfma(K, Q) -> S^T[kv][q]; lane's col (lane&15) = its q-row,
// so row-max/sum are in-lane (+2 shuffles); P stays in registers and feeds PV's
// A-fragment under a kv-permutation pi; V is read under the same pi (2x ds_read_b64).
// No P-LDS roundtrip, no per-tile row shuffles. Q pre-scaled (exp2 domain).
__global__ __launch_bounds__(256) void k_attn(const __bf16* __restrict__ q,
                                              const __bf16* __restrict__ k,
                                              const __bf16* __restrict__ vt,
                                              __bf16* __restrict__ out) {
  __shared__ __align__(16) char lsK[2][8192];   // [64 kv][64 d] bf16, swizzled rows
  __shared__ __align__(16) char lsV[2][8192];   // [64 d][64 kv] bf16, swizzled rows

  const int tid  = threadIdx.x;
  const int lane = tid & 63;
  const int wid  = tid >> 6;
  const int lr   = lane & 15;
  const int lk   = lane >> 4;

  const int bh = blockIdx.y;
  const int b  = bh / NH, h = bh - b*NH;
  const int qi  = (blockIdx.x + 5*(blockIdx.y >> 4)) & 15;   // spread sizes across CUs
  const int qb0 = qi * 128;
  const int q0w = qb0 + wid * 32;

  const __bf16* qh = q + (size_t)bh*SEQ*DKH;
  const char*   kB = (const char*)(k  + (size_t)bh*SEQ*DKH);
  const char*   vB = (const char*)(vt + (size_t)bh*DKH*SEQ);

  // Q fragments (B-operand of swapped QK): lane holds Q[q0w+16r+lr][32c + 8lk .. +7]
  bf16x8 bq[2][2];
  #pragma unroll
  for (int r = 0; r < 2; ++r)
    #pragma unroll
    for (int c = 0; c < 2; ++c)
      bq[r][c] = *(const bf16x8*)(qh + (size_t)(q0w + r*16 + lr)*DKH + c*32 + lk*8);

  // O accumulators: o[r][df]: rows q = q0w+16r+4lk+j, col d = df*16+lr
  f32x4 o[2][4];
  #pragma unroll
  for (int r = 0; r < 2; ++r)
    #pragma unroll
    for (int df = 0; df < 4; ++df) { f32x4 z = {0.f,0.f,0.f,0.f}; o[r][df] = z; }
  // softmax state: one q-row per (r): q = q0w + 16r + lr
  float m_i[2] = {-1e30f, -1e30f};
  float l_ln[2] = {0.f, 0.f};          // per-lane partial row sum (kv-slice local)

  const int nt = qb0/64 + 2;           // kv tiles: [0, qb0+128)

  auto stage = [&](int buf, int kv0) {
    #pragma unroll
    for (int c = 0; c < 2; ++c) {
      int chunk = wid*2 + c;                 // 0..7, 1024B each
      int lb    = chunk*1024 + lane*16;      // linear dest byte in tile
      int row   = lb >> 7;                   // 128B rows
      int colb  = (lb & 127) ^ ((row & 7) << 4);  // pre-swizzled source column
      __builtin_amdgcn_global_load_lds(
        (const __attribute__((address_space(1))) void*)(kB + (size_t)(kv0 + row)*128 + colb),
        (__attribute__((address_space(3))) void*)(lsK[buf] + chunk*1024), 16, 0, 0);
      __builtin_amdgcn_global_load_lds(
        (const __attribute__((address_space(1))) void*)(vB + (size_t)row*(SEQ*2) + (size_t)kv0*2 + colb),
        (__attribute__((address_space(3))) void*)(lsV[buf] + chunk*1024), 16, 0, 0);
    }
  };

  stage(0, 0);
  __syncthreads();
  int cur = 0;

  for (int t = 0; t < nt; ++t) {
    const int kv0 = t * 64;
    if (t + 1 < nt) stage(cur ^ 1, kv0 + 64);

    if (kv0 <= q0w + 31) {          // wave-uniform causal activity
      // ---- S^T = K Q^T : tiles n (kv), C[kv][q]: lane q-col=lr, kv-row=16n+4lk+j ----
      f32x4 sc[2][4];
      #pragma unroll
      for (int r = 0; r < 2; ++r)
        #pragma unroll
        for (int n = 0; n < 4; ++n) { f32x4 z = {0.f,0.f,0.f,0.f}; sc[r][n] = z; }
      #pragma unroll
      for (int n = 0; n < 4; ++n) {
        int kvl = n*16 + lr;
        const char* kr = lsK[cur] + kvl*128;
        int sw = (kvl & 7) << 4;
        bf16x8 ak0 = *(const bf16x8*)(kr + ((lk*16) ^ sw));       // K[kvl][8lk..], c=0
        bf16x8 ak1 = *(const bf16x8*)(kr + ((64 + lk*16) ^ sw));  // c=1
        #pragma unroll
        for (int r = 0; r < 2; ++r) {
          sc[r][n] = __builtin_amdgcn_mfma_f32_16x16x32_bf16(ak0, bq[r][0], sc[r][n], 0, 0, 0);
          sc[r][n] = __builtin_amdgcn_mfma_f32_16x16x32_bf16(ak1, bq[r][1], sc[r][n], 0, 0, 0);
        }
      }
      // ---- causal mask (diag tiles only): kv = kv0+16n+4lk+j, q = q0w+16r+lr ----
      if (kv0 + 63 > q0w) {
        #pragma unroll
        for (int r = 0; r < 2; ++r) {
          int qrow = q0w + r*16 + lr;
          #pragma unroll
          for (int n = 0; n < 4; ++n) {
            int kvb = kv0 + n*16 + lk*4;
            #pragma unroll
            for (int j = 0; j < 4; ++j)
              if (kvb + j > qrow) sc[r][n][j] = -1e30f;
          }
        }
      }
      // ---- row max: in-lane over 16, then across lk groups (2 shuffles) ----
      float pm[2];
      #pragma unroll
      for (int r = 0; r < 2; ++r) {
        float v = sc[r][0][0];
        #pragma unroll
        for (int n = 0; n < 4; ++n)
          #pragma unroll
          for (int j = 0; j < 4; ++j)
            v = fmaxf(v, sc[r][n][j]);
        v = fmaxf(v, __shfl_xor(v, 16));
        v = fmaxf(v, __shfl_xor(v, 32));
        pm[r] = v;
      }
      // ---- defer-max (T13) ----
      bool need = (pm[0] > m_i[0] + 8.0f) || (pm[1] > m_i[1] + 8.0f);
      if (__any(need)) {
        float alpha[2];
        #pragma unroll
        for (int r = 0; r < 2; ++r) {
          float mn = fmaxf(m_i[r], pm[r]);
          alpha[r] = exp2f(m_i[r] - mn);
          m_i[r] = mn;
          l_ln[r] *= alpha[r];
        }
        // o rows are q=4lk+j: fetch alpha from lane lr'=4lk+j in own lk group
        #pragma unroll
        for (int r = 0; r < 2; ++r) {
          #pragma unroll
          for (int j = 0; j < 4; ++j) {
            float av = __shfl(alpha[r], (lane & 48) | (((lane >> 4) & 3) * 4 + j));
            #pragma unroll
            for (int df = 0; df < 4; ++df) o[r][df][j] *= av;
          }
        }
      }
      // ---- P = exp2(s - m) in-register; build PV A-frags under kv-permutation pi ----
      // frag pa[r][c][t] = P at kv-tile n = 2c + (t>>2), j = t&3 (lane's own values)
      bf16x8 pa[2][2];
      #pragma unroll
      for (int r = 0; r < 2; ++r) {
        float pv[4][4];
        #pragma unroll
        for (int n = 0; n < 4; ++n)
          #pragma unroll
          for (int j = 0; j < 4; ++j) {
            float e = exp2f(sc[r][n][j] - m_i[r]);
            pv[n][j] = e;
            l_ln[r] += e;
          }
        #pragma unroll
        for (int c = 0; c < 2; ++c)
          #pragma unroll
          for (int t = 0; t < 8; ++t)
            pa[r][c][t] = (__bf16)pv[2*c + (t>>2)][t & 3];
      }
      // ---- O += P V with V read under pi: lane needs V[kv0+32c+{4lk..+3, 16+4lk..+3}][d] ----
      #pragma unroll
      for (int df = 0; df < 4; ++df) {
        int d = df*16 + lr;
        const char* vr = lsV[cur] + d*128;
        int sw = (d & 7) << 4;
        #pragma unroll
        for (int c = 0; c < 2; ++c) {
          bf16x4 v0 = *(const bf16x4*)(vr + ((c*64 + lk*8) ^ sw));
          bf16x4 v1 = *(const bf16x4*)(vr + ((c*64 + 32 + lk*8) ^ sw));
          bf16x8 bv = {v0[0], v0[1], v0[2], v0[3], v1[0], v1[1], v1[2], v1[3]};
          #pragma unroll
          for (int r = 0; r < 2; ++r)
            o[r][df] = __builtin_amdgcn_mfma_f32_16x16x32_bf16(pa[r][c], bv, o[r][df], 0, 0, 0);
        }
      }
    }
    __syncthreads();
    cur ^= 1;
  }

  // ---- epilogue: reduce l across lk groups, invert, redistribute to o rows, store ----
  float inv[2];
  #pragma unroll
  for (int r = 0; r < 2; ++r) {
    float v = l_ln[r];
    v += __shfl_xor(v, 16);
    v += __shfl_xor(v, 32);
    inv[r] = 1.0f / v;
  }
  #pragma unroll
  for (int r = 0; r < 2; ++r) {
    float iv[4];
    #pragma unroll
    for (int j = 0; j < 4; ++j)
      iv[j] = __shfl(inv[r], (lane & 48) | (((lane >> 4) & 3) * 4 + j));
    #pragma unroll
    for (int df = 0; df < 4; ++df) {
      int d = df*16 + lr;
      #pragma unroll
      for (int j = 0; j < 4; ++j) {
        int ss = q0w + r*16 + ((lane >> 4) & 3)*4 + j;
        out[((size_t)b*SEQ + ss)*D_MODEL + h*DKH + d] = (__bf16)(o[r][df][j] * iv[j]);
      }
    }
  }
}

// ---------------- launch ----------------
extern "C" void kernel_launch(void* const* d_in, const int* in_sizes, int n_in,
                              void* d_out, int out_size, void* d_ws, size_t ws_size,
                              hipStream_t stream) {
  const float* x    = (const float*)d_in[0];
  /* d_in[1] = causal mask, implemented analytically */
  const float* Wqkv = (const float*)d_in[2];
  const float* bqkv = (const float*)d_in[3];
  const float* Wout = (const float*)d_in[4];
  const float* bout = (const float*)d_in[5];
  float* out = (float*)d_out;

  char* w = (char*)d_ws;
  __bf16* xb    = (__bf16*)w; w += (size_t)ROWS*D_MODEL*2;
  __bf16* wqkvT = (__bf16*)w; w += (size_t)N_QKV*D_MODEL*2;
  __bf16* woutT = (__bf16*)w; w += (size_t)D_MODEL*D_MODEL*2;
  __bf16* qb    = (__bf16*)w; w += (size_t)BATCH*NH*SEQ*DKH*2;
  __bf16* kb    = (__bf16*)w; w += (size_t)BATCH*NH*SEQ*DKH*2;
  __bf16* vtb   = (__bf16*)w; w += (size_t)BATCH*NH*SEQ*DKH*2;
  __bf16* attnb = (__bf16*)w; w += (size_t)ROWS*D_MODEL*2;

  k_convert<<<(ROWS*D_MODEL/4 + 255)/256, 256, 0, stream>>>(x, xb, ROWS*D_MODEL);
  k_transpose<<<dim3(N_QKV/32, D_MODEL/32), dim3(32, 8), 0, stream>>>(Wqkv, wqkvT, D_MODEL, N_QKV);
  k_transpose<<<dim3(D_MODEL/32, D_MODEL/32), dim3(32, 8), 0, stream>>>(Wout, woutT, D_MODEL, D_MODEL);
  k_gemm_qkv<<<dim3(N_QKV/128, ROWS/128), 256, 0, stream>>>(xb, wqkvT, bqkv, qb, kb, vtb);
  k_attn<<<dim3(16, BATCH*NH), 256, 0, stream>>>(qb, kb, vtb, attnb);
  k_gemm_out<<<dim3(D_MODEL/128, ROWS/128), 256, 0, stream>>>(attnb, woutT, bout, out);
}

// Round 7
// 188.540 us; speedup vs baseline: 1.8085x; 1.0491x over previous
//
#include <hip/hip_runtime.h>

typedef __bf16 bf16x8 __attribute__((ext_vector_type(8)));
typedef __bf16 bf16x4 __attribute__((ext_vector_type(4)));
typedef float f32x4 __attribute__((ext_vector_type(4)));

#define D_MODEL 768
#define NH 12
#define DKH 64
#define BATCH 4
#define SEQ 2048
#define ROWS (BATCH*SEQ)   /* 8192 */
#define N_QKV (3*D_MODEL)  /* 2304 */
#define QSCALE 0.18033688f /* 0.125 * log2(e): folds softmax scale + exp2 domain into Q */

// ---------------- convert fp32 -> bf16 ----------------
__global__ void k_convert(const float* __restrict__ in, __bf16* __restrict__ out, int n) {
  int i = (blockIdx.x * blockDim.x + threadIdx.x) * 4;
  if (i >= n) return;
  float4 v = *(const float4*)(in + i);
  out[i+0] = (__bf16)v.x; out[i+1] = (__bf16)v.y;
  out[i+2] = (__bf16)v.z; out[i+3] = (__bf16)v.w;
}

// ---------------- transpose fp32 [R][C] -> bf16 [C][R] ----------------
__global__ void k_transpose(const float* __restrict__ in, __bf16* __restrict__ out, int R, int C) {
  __shared__ float tile[32][33];
  int c0 = blockIdx.x * 32, r0 = blockIdx.y * 32;
  int tx = threadIdx.x, ty = threadIdx.y;   // (32, 8)
  #pragma unroll
  for (int i = 0; i < 4; ++i) {
    int r = ty + i*8;
    tile[r][tx] = in[(size_t)(r0 + r)*C + c0 + tx];
  }
  __syncthreads();
  #pragma unroll
  for (int i = 0; i < 4; ++i) {
    int c = ty + i*8;
    out[(size_t)(c0 + c)*R + r0 + tx] = (__bf16)tile[tx][c];
  }
}

// ---------------- GEMM core: 2-phase double-buffered 128x128 tile ----------------
__device__ __forceinline__ void gemm_stage(const __bf16* __restrict__ A, int lda,
                                           const __bf16* __restrict__ Bt, int ldb,
                                           int m0, int n0, int kt,
                                           __bf16* lA, __bf16* lB) {
  const int tid  = threadIdx.x;
  const int lane = tid & 63;
  const int wid  = tid >> 6;
  #pragma unroll
  for (int c = 0; c < 2; ++c) {
    int chunk = wid*2 + c;               // 0..7
    int bo = chunk*1024 + lane*16;       // byte offset in tile
    int m  = bo >> 6;                    // 64B per row
    int kb = (bo & 63) >> 1;             // element in row
    __builtin_amdgcn_global_load_lds(
      (const __attribute__((address_space(1))) void*)(A + (size_t)(m0 + m)*lda + kt + kb),
      (__attribute__((address_space(3))) void*)(lA + chunk*512), 16, 0, 0);
    __builtin_amdgcn_global_load_lds(
      (const __attribute__((address_space(1))) void*)(Bt + (size_t)(n0 + m)*ldb + kt + kb),
      (__attribute__((address_space(3))) void*)(lB + chunk*512), 16, 0, 0);
  }
}

__device__ __forceinline__ void gemm_core(const __bf16* __restrict__ A, int lda,
                                          const __bf16* __restrict__ Bt, int ldb,
                                          int K, int m0, int n0,
                                          __bf16* lA, __bf16* lB, f32x4 acc[4][4]) {
  const int lane = threadIdx.x & 63;
  const int wid  = threadIdx.x >> 6;
  const int wm   = (wid >> 1) * 64;
  const int wn   = (wid & 1) * 64;
  const int lr   = lane & 15;
  const int lk   = lane >> 4;

  gemm_stage(A, lda, Bt, ldb, m0, n0, 0, lA, lB);
  __syncthreads();
  int cur = 0;
  for (int kt = 0; kt < K; kt += 32) {
    if (kt + 32 < K)
      gemm_stage(A, lda, Bt, ldb, m0, n0, kt + 32, lA + (cur^1)*4096, lB + (cur^1)*4096);
    const __bf16* cA = lA + cur*4096;
    const __bf16* cB = lB + cur*4096;
    bf16x8 af[4], bfr[4];
    #pragma unroll
    for (int i = 0; i < 4; ++i) {
      af[i]  = *(const bf16x8*)(cA + (wm + i*16 + lr)*32 + lk*8);
      bfr[i] = *(const bf16x8*)(cB + (wn + i*16 + lr)*32 + lk*8);
    }
    #pragma unroll
    for (int mi = 0; mi < 4; ++mi)
      #pragma unroll
      for (int ni = 0; ni < 4; ++ni)
        acc[mi][ni] = __builtin_amdgcn_mfma_f32_16x16x32_bf16(af[mi], bfr[ni], acc[mi][ni], 0, 0, 0);
    __syncthreads();
    cur ^= 1;
  }
}

// ---------------- GEMM1: qkv = xb @ WqkvT + bqkv, scatter to Q(scaled),K,V^T ----------------
__global__ __launch_bounds__(256) void k_gemm_qkv(const __bf16* __restrict__ xb,
                                                  const __bf16* __restrict__ wT,
                                                  const float* __restrict__ bias,
                                                  __bf16* __restrict__ qb,
                                                  __bf16* __restrict__ kb,
                                                  __bf16* __restrict__ vtb) {
  __shared__ __align__(16) __bf16 lA[2*128*32];
  __shared__ __align__(16) __bf16 lB[2*128*32];
  f32x4 acc[4][4];
  #pragma unroll
  for (int i = 0; i < 4; ++i)
    #pragma unroll
    for (int j = 0; j < 4; ++j) { f32x4 z = {0.f,0.f,0.f,0.f}; acc[i][j] = z; }

  const int m0 = blockIdx.y * 128, n0 = blockIdx.x * 128;
  gemm_core(xb, D_MODEL, wT, D_MODEL, D_MODEL, m0, n0, lA, lB, acc);

  const int lane = threadIdx.x & 63;
  const int wid  = threadIdx.x >> 6;
  const int wm = (wid >> 1) * 64, wn = (wid & 1) * 64;
  const int lr = lane & 15, lk = lane >> 4;
  #pragma unroll
  for (int mi = 0; mi < 4; ++mi) {
    #pragma unroll
    for (int ni = 0; ni < 4; ++ni) {
      int col = n0 + wn + ni*16 + lr;
      int t   = col / D_MODEL;
      int r2  = col - t*D_MODEL;
      int hh  = r2 >> 6, dk = r2 & 63;
      float bv = bias[col];
      #pragma unroll
      for (int j = 0; j < 4; ++j) {
        int row = m0 + wm + mi*16 + lk*4 + j;
        int bb = row >> 11, ss = row & 2047;
        float fv = acc[mi][ni][j] + bv;
        if (t == 0)      qb [(((size_t)bb*NH + hh)*SEQ + ss)*DKH + dk] = (__bf16)(fv * QSCALE);
        else if (t == 1) kb [(((size_t)bb*NH + hh)*SEQ + ss)*DKH + dk] = (__bf16)fv;
        else             vtb[(((size_t)bb*NH + hh)*DKH + dk)*SEQ + ss] = (__bf16)fv;
      }
    }
  }
}

// ---------------- GEMM3: out = attn @ WoutT + bout (fp32 out) ----------------
__global__ __launch_bounds__(256) void k_gemm_out(const __bf16* __restrict__ ab,
                                                  const __bf16* __restrict__ wT,
                                                  const float* __restrict__ bias,
                                                  float* __restrict__ out) {
  __shared__ __align__(16) __bf16 lA[2*128*32];
  __shared__ __align__(16) __bf16 lB[2*128*32];
  f32x4 acc[4][4];
  #pragma unroll
  for (int i = 0; i < 4; ++i)
    #pragma unroll
    for (int j = 0; j < 4; ++j) { f32x4 z = {0.f,0.f,0.f,0.f}; acc[i][j] = z; }

  const int m0 = blockIdx.y * 128, n0 = blockIdx.x * 128;
  gemm_core(ab, D_MODEL, wT, D_MODEL, D_MODEL, m0, n0, lA, lB, acc);

  const int lane = threadIdx.x & 63;
  const int wid  = threadIdx.x >> 6;
  const int wm = (wid >> 1) * 64, wn = (wid & 1) * 64;
  const int lr = lane & 15, lk = lane >> 4;
  #pragma unroll
  for (int mi = 0; mi < 4; ++mi) {
    #pragma unroll
    for (int ni = 0; ni < 4; ++ni) {
      int col = n0 + wn + ni*16 + lr;
      float bv = bias[col];
      #pragma unroll
      for (int j = 0; j < 4; ++j) {
        int row = m0 + wm + mi*16 + lk*4 + j;
        out[(size_t)row*D_MODEL + col] = acc[mi][ni][j] + bv;
      }
    }
  }
}

// Balanced qi map: three permutations of 0..15 with column sums 22/23.
// With grid (16,48) dispatched x-major, CU c (round-robin over 256) hosts the
// blocks with the SAME bx and by in {v, v+16, v+32} -> rows 0,1,2 of this table
// at one column -> per-CU causal work constant -> no drain tail.
__device__ const int QI_TAB[3][16] = {
  { 0, 1, 2, 3, 4, 5, 6, 7, 8, 9,10,11,12,13,14,15},
  { 8, 9,10,11,12,13,14,15, 1, 2, 3, 4, 5, 6, 7, 0},
  {15,13,11, 9, 6, 4, 2, 0,14,12,10, 7, 5, 3, 1, 8}
};

// ---------------- Flash attention (causal), swapped-QK in-register softmax ----------------
// grid (16, 48), 4 waves x 32 q-rows, KVBLK=64, K/V^T LDS dbuf (swizzled, R5 layout).
// QK^T computed SWAPPED: mfma(K, Q) -> S^T[kv][q]; softmax in-lane; P stays in
// registers and feeds PV's A-fragment under kv-permutation pi; V read under pi.
// Q pre-scaled (exp2 domain). T5 setprio around MFMA clusters. QI_TAB balance.
__global__ __launch_bounds__(256) void k_attn(const __bf16* __restrict__ q,
                                              const __bf16* __restrict__ k,
                                              const __bf16* __restrict__ vt,
                                              __bf16* __restrict__ out) {
  __shared__ __align__(16) char lsK[2][8192];   // [64 kv][64 d] bf16, swizzled rows
  __shared__ __align__(16) char lsV[2][8192];   // [64 d][64 kv] bf16, swizzled rows

  const int tid  = threadIdx.x;
  const int lane = tid & 63;
  const int wid  = tid >> 6;
  const int lr   = lane & 15;
  const int lk   = lane >> 4;

  const int bh = blockIdx.y;
  const int b  = bh / NH, h = bh - b*NH;
  const int qi  = QI_TAB[blockIdx.y >> 4][blockIdx.x];
  const int qb0 = qi * 128;
  const int q0w = qb0 + wid * 32;

  const __bf16* qh = q + (size_t)bh*SEQ*DKH;
  const char*   kB = (const char*)(k  + (size_t)bh*SEQ*DKH);
  const char*   vB = (const char*)(vt + (size_t)bh*DKH*SEQ);

  // Q fragments (B-operand of swapped QK): lane holds Q[q0w+16r+lr][32c + 8lk .. +7]
  bf16x8 bq[2][2];
  #pragma unroll
  for (int r = 0; r < 2; ++r)
    #pragma unroll
    for (int c = 0; c < 2; ++c)
      bq[r][c] = *(const bf16x8*)(qh + (size_t)(q0w + r*16 + lr)*DKH + c*32 + lk*8);

  // O accumulators: o[r][df]: rows q = q0w+16r+4lk+j, col d = df*16+lr
  f32x4 o[2][4];
  #pragma unroll
  for (int r = 0; r < 2; ++r)
    #pragma unroll
    for (int df = 0; df < 4; ++df) { f32x4 z = {0.f,0.f,0.f,0.f}; o[r][df] = z; }
  // softmax state: one q-row per (r): q = q0w + 16r + lr
  float m_i[2] = {-1e30f, -1e30f};
  float l_ln[2] = {0.f, 0.f};          // per-lane partial row sum (kv-slice local)

  const int nt = qb0/64 + 2;           // kv tiles: [0, qb0+128)

  auto stage = [&](int buf, int kv0) {
    #pragma unroll
    for (int c = 0; c < 2; ++c) {
      int chunk = wid*2 + c;                 // 0..7, 1024B each
      int lb    = chunk*1024 + lane*16;      // linear dest byte in tile
      int row   = lb >> 7;                   // 128B rows
      int colb  = (lb & 127) ^ ((row & 7) << 4);  // pre-swizzled source column (16B granular)
      __builtin_amdgcn_global_load_lds(
        (const __attribute__((address_space(1))) void*)(kB + (size_t)(kv0 + row)*128 + colb),
        (__attribute__((address_space(3))) void*)(lsK[buf] + chunk*1024), 16, 0, 0);
      __builtin_amdgcn_global_load_lds(
        (const __attribute__((address_space(1))) void*)(vB + (size_t)row*(SEQ*2) + (size_t)kv0*2 + colb),
        (__attribute__((address_space(3))) void*)(lsV[buf] + chunk*1024), 16, 0, 0);
    }
  };

  stage(0, 0);
  __syncthreads();
  int cur = 0;

  for (int t = 0; t < nt; ++t) {
    const int kv0 = t * 64;
    if (t + 1 < nt) stage(cur ^ 1, kv0 + 64);

    if (kv0 <= q0w + 31) {          // wave-uniform causal activity
      // ---- S^T = K Q^T : C[kv][q]: lane q-col=lr, kv-row=16n+4lk+j ----
      f32x4 sc[2][4];
      #pragma unroll
      for (int r = 0; r < 2; ++r)
        #pragma unroll
        for (int n = 0; n < 4; ++n) { f32x4 z = {0.f,0.f,0.f,0.f}; sc[r][n] = z; }
      __builtin_amdgcn_s_setprio(1);
      #pragma unroll
      for (int n = 0; n < 4; ++n) {
        int kvl = n*16 + lr;
        const char* kr = lsK[cur] + kvl*128;
        int sw = (kvl & 7) << 4;
        bf16x8 ak0 = *(const bf16x8*)(kr + ((lk*16) ^ sw));       // K[kvl][8lk..], c=0
        bf16x8 ak1 = *(const bf16x8*)(kr + ((64 + lk*16) ^ sw));  // c=1
        #pragma unroll
        for (int r = 0; r < 2; ++r) {
          sc[r][n] = __builtin_amdgcn_mfma_f32_16x16x32_bf16(ak0, bq[r][0], sc[r][n], 0, 0, 0);
          sc[r][n] = __builtin_amdgcn_mfma_f32_16x16x32_bf16(ak1, bq[r][1], sc[r][n], 0, 0, 0);
        }
      }
      __builtin_amdgcn_s_setprio(0);
      // ---- causal mask (diag tiles only): kv = kv0+16n+4lk+j, q = q0w+16r+lr ----
      if (kv0 + 63 > q0w) {
        #pragma unroll
        for (int r = 0; r < 2; ++r) {
          int qrow = q0w + r*16 + lr;
          #pragma unroll
          for (int n = 0; n < 4; ++n) {
            int kvb = kv0 + n*16 + lk*4;
            #pragma unroll
            for (int j = 0; j < 4; ++j)
              if (kvb + j > qrow) sc[r][n][j] = -1e30f;
          }
        }
      }
      // ---- row max: in-lane over 16, then across lk groups (2 shuffles) ----
      float pm[2];
      #pragma unroll
      for (int r = 0; r < 2; ++r) {
        float v = sc[r][0][0];
        #pragma unroll
        for (int n = 0; n < 4; ++n)
          #pragma unroll
          for (int j = 0; j < 4; ++j)
            v = fmaxf(v, sc[r][n][j]);
        v = fmaxf(v, __shfl_xor(v, 16));
        v = fmaxf(v, __shfl_xor(v, 32));
        pm[r] = v;
      }
      // ---- defer-max (T13) ----
      bool need = (pm[0] > m_i[0] + 8.0f) || (pm[1] > m_i[1] + 8.0f);
      if (__any(need)) {
        float alpha[2];
        #pragma unroll
        for (int r = 0; r < 2; ++r) {
          float mn = fmaxf(m_i[r], pm[r]);
          alpha[r] = exp2f(m_i[r] - mn);
          m_i[r] = mn;
          l_ln[r] *= alpha[r];
        }
        // o rows are q=4lk+j: fetch alpha from lane lr'=4lk+j in own lk group
        #pragma unroll
        for (int r = 0; r < 2; ++r) {
          #pragma unroll
          for (int j = 0; j < 4; ++j) {
            float av = __shfl(alpha[r], (lane & 48) | (((lane >> 4) & 3) * 4 + j));
            #pragma unroll
            for (int df = 0; df < 4; ++df) o[r][df][j] *= av;
          }
        }
      }
      // ---- P = exp2(s - m) in-register; build PV A-frags under kv-permutation pi ----
      bf16x8 pa[2][2];
      #pragma unroll
      for (int r = 0; r < 2; ++r) {
        float pv[4][4];
        #pragma unroll
        for (int n = 0; n < 4; ++n)
          #pragma unroll
          for (int j = 0; j < 4; ++j) {
            float e = exp2f(sc[r][n][j] - m_i[r]);
            pv[n][j] = e;
            l_ln[r] += e;
          }
        #pragma unroll
        for (int c = 0; c < 2; ++c)
          #pragma unroll
          for (int t2 = 0; t2 < 8; ++t2)
            pa[r][c][t2] = (__bf16)pv[2*c + (t2>>2)][t2 & 3];
      }
      // ---- O += P V with V read under pi (R5 swizzle) ----
      __builtin_amdgcn_s_setprio(1);
      #pragma unroll
      for (int df = 0; df < 4; ++df) {
        int d = df*16 + lr;
        const char* vr = lsV[cur] + d*128;
        int sw = (d & 7) << 4;
        #pragma unroll
        for (int c = 0; c < 2; ++c) {
          bf16x4 v0 = *(const bf16x4*)(vr + ((c*64 + lk*8) ^ sw));
          bf16x4 v1 = *(const bf16x4*)(vr + ((c*64 + 32 + lk*8) ^ sw));
          bf16x8 bv = {v0[0], v0[1], v0[2], v0[3], v1[0], v1[1], v1[2], v1[3]};
          #pragma unroll
          for (int r = 0; r < 2; ++r)
            o[r][df] = __builtin_amdgcn_mfma_f32_16x16x32_bf16(pa[r][c], bv, o[r][df], 0, 0, 0);
        }
      }
      __builtin_amdgcn_s_setprio(0);
    }
    __syncthreads();
    cur ^= 1;
  }

  // ---- epilogue: reduce l across lk groups, invert, redistribute to o rows, store ----
  float inv[2];
  #pragma unroll
  for (int r = 0; r < 2; ++r) {
    float v = l_ln[r];
    v += __shfl_xor(v, 16);
    v += __shfl_xor(v, 32);
    inv[r] = 1.0f / v;
  }
  #pragma unroll
  for (int r = 0; r < 2; ++r) {
    float iv[4];
    #pragma unroll
    for (int j = 0; j < 4; ++j)
      iv[j] = __shfl(inv[r], (lane & 48) | (((lane >> 4) & 3) * 4 + j));
    #pragma unroll
    for (int df = 0; df < 4; ++df) {
      int d = df*16 + lr;
      #pragma unroll
      for (int j = 0; j < 4; ++j) {
        int ss = q0w + r*16 + ((lane >> 4) & 3)*4 + j;
        out[((size_t)b*SEQ + ss)*D_MODEL + h*DKH + d] = (__bf16)(o[r][df][j] * iv[j]);
      }
    }
  }
}

// ---------------- launch ----------------
extern "C" void kernel_launch(void* const* d_in, const int* in_sizes, int n_in,
                              void* d_out, int out_size, void* d_ws, size_t ws_size,
                              hipStream_t stream) {
  const float* x    = (const float*)d_in[0];
  /* d_in[1] = causal mask, implemented analytically */
  const float* Wqkv = (const float*)d_in[2];
  const float* bqkv = (const float*)d_in[3];
  const float* Wout = (const float*)d_in[4];
  const float* bout = (const float*)d_in[5];
  float* out = (float*)d_out;

  char* w = (char*)d_ws;
  __bf16* xb    = (__bf16*)w; w += (size_t)ROWS*D_MODEL*2;
  __bf16* wqkvT = (__bf16*)w; w += (size_t)N_QKV*D_MODEL*2;
  __bf16* woutT = (__bf16*)w; w += (size_t)D_MODEL*D_MODEL*2;
  __bf16* qb    = (__bf16*)w; w += (size_t)BATCH*NH*SEQ*DKH*2;
  __bf16* kb    = (__bf16*)w; w += (size_t)BATCH*NH*SEQ*DKH*2;
  __bf16* vtb   = (__bf16*)w; w += (size_t)BATCH*NH*SEQ*DKH*2;
  __bf16* attnb = (__bf16*)w; w += (size_t)ROWS*D_MODEL*2;

  k_convert<<<(ROWS*D_MODEL/4 + 255)/256, 256, 0, stream>>>(x, xb, ROWS*D_MODEL);
  k_transpose<<<dim3(N_QKV/32, D_MODEL/32), dim3(32, 8), 0, stream>>>(Wqkv, wqkvT, D_MODEL, N_QKV);
  k_transpose<<<dim3(D_MODEL/32, D_MODEL/32), dim3(32, 8), 0, stream>>>(Wout, woutT, D_MODEL, D_MODEL);
  k_gemm_qkv<<<dim3(N_QKV/128, ROWS/128), 256, 0, stream>>>(xb, wqkvT, bqkv, qb, kb, vtb);
  k_attn<<<dim3(16, BATCH*NH), 256, 0, stream>>>(qb, kb, vtb, attnb);
  k_gemm_out<<<dim3(D_MODEL/128, ROWS/128), 256, 0, stream>>>(attnb, woutT, bout, out);
}

// Round 8
// 172.695 us; speedup vs baseline: 1.9744x; 1.0918x over previous
//
#include <hip/hip_runtime.h>

typedef __bf16 bf16x8 __attribute__((ext_vector_type(8)));
typedef __bf16 bf16x4 __attribute__((ext_vector_type(4)));
typedef float f32x4 __attribute__((ext_vector_type(4)));

#define D_MODEL 768
#define NH 12
#define DKH 64
#define BATCH 4
#define SEQ 2048
#define ROWS (BATCH*SEQ)   /* 8192 */
#define N_QKV (3*D_MODEL)  /* 2304 */
#define QSCALE 0.18033688f /* 0.125 * log2(e): folds softmax scale + exp2 domain into Q */

// ---------------- convert fp32 -> bf16 ----------------
__global__ void k_convert(const float* __restrict__ in, __bf16* __restrict__ out, int n) {
  int i = (blockIdx.x * blockDim.x + threadIdx.x) * 4;
  if (i >= n) return;
  float4 v = *(const float4*)(in + i);
  out[i+0] = (__bf16)v.x; out[i+1] = (__bf16)v.y;
  out[i+2] = (__bf16)v.z; out[i+3] = (__bf16)v.w;
}

// ---------------- transpose fp32 [R][C] -> bf16 [C][R] ----------------
__global__ void k_transpose(const float* __restrict__ in, __bf16* __restrict__ out, int R, int C) {
  __shared__ float tile[32][33];
  int c0 = blockIdx.x * 32, r0 = blockIdx.y * 32;
  int tx = threadIdx.x, ty = threadIdx.y;   // (32, 8)
  #pragma unroll
  for (int i = 0; i < 4; ++i) {
    int r = ty + i*8;
    tile[r][tx] = in[(size_t)(r0 + r)*C + c0 + tx];
  }
  __syncthreads();
  #pragma unroll
  for (int i = 0; i < 4; ++i) {
    int c = ty + i*8;
    out[(size_t)(c0 + c)*R + r0 + tx] = (__bf16)tile[tx][c];
  }
}

// ---------------- GEMM core: 2-phase double-buffered 128x128 tile ----------------
__device__ __forceinline__ void gemm_stage(const __bf16* __restrict__ A, int lda,
                                           const __bf16* __restrict__ Bt, int ldb,
                                           int m0, int n0, int kt,
                                           __bf16* lA, __bf16* lB) {
  const int tid  = threadIdx.x;
  const int lane = tid & 63;
  const int wid  = tid >> 6;
  #pragma unroll
  for (int c = 0; c < 2; ++c) {
    int chunk = wid*2 + c;               // 0..7
    int bo = chunk*1024 + lane*16;       // byte offset in tile
    int m  = bo >> 6;                    // 64B per row
    int kb = (bo & 63) >> 1;             // element in row
    __builtin_amdgcn_global_load_lds(
      (const __attribute__((address_space(1))) void*)(A + (size_t)(m0 + m)*lda + kt + kb),
      (__attribute__((address_space(3))) void*)(lA + chunk*512), 16, 0, 0);
    __builtin_amdgcn_global_load_lds(
      (const __attribute__((address_space(1))) void*)(Bt + (size_t)(n0 + m)*ldb + kt + kb),
      (__attribute__((address_space(3))) void*)(lB + chunk*512), 16, 0, 0);
  }
}

__device__ __forceinline__ void gemm_core(const __bf16* __restrict__ A, int lda,
                                          const __bf16* __restrict__ Bt, int ldb,
                                          int K, int m0, int n0,
                                          __bf16* lA, __bf16* lB, f32x4 acc[4][4]) {
  const int lane = threadIdx.x & 63;
  const int wid  = threadIdx.x >> 6;
  const int wm   = (wid >> 1) * 64;
  const int wn   = (wid & 1) * 64;
  const int lr   = lane & 15;
  const int lk   = lane >> 4;

  gemm_stage(A, lda, Bt, ldb, m0, n0, 0, lA, lB);
  __syncthreads();
  int cur = 0;
  for (int kt = 0; kt < K; kt += 32) {
    if (kt + 32 < K)
      gemm_stage(A, lda, Bt, ldb, m0, n0, kt + 32, lA + (cur^1)*4096, lB + (cur^1)*4096);
    const __bf16* cA = lA + cur*4096;
    const __bf16* cB = lB + cur*4096;
    bf16x8 af[4], bfr[4];
    #pragma unroll
    for (int i = 0; i < 4; ++i) {
      af[i]  = *(const bf16x8*)(cA + (wm + i*16 + lr)*32 + lk*8);
      bfr[i] = *(const bf16x8*)(cB + (wn + i*16 + lr)*32 + lk*8);
    }
    #pragma unroll
    for (int mi = 0; mi < 4; ++mi)
      #pragma unroll
      for (int ni = 0; ni < 4; ++ni)
        acc[mi][ni] = __builtin_amdgcn_mfma_f32_16x16x32_bf16(af[mi], bfr[ni], acc[mi][ni], 0, 0, 0);
    __syncthreads();
    cur ^= 1;
  }
}

// ---------------- GEMM1: qkv = xb @ WqkvT + bqkv, scatter to Q(scaled),K,V^T ----------------
// grid flattened 1152 blocks; T1 XCD-aware bijective swizzle (1152 % 8 == 0).
__global__ __launch_bounds__(256) void k_gemm_qkv(const __bf16* __restrict__ xb,
                                                  const __bf16* __restrict__ wT,
                                                  const float* __restrict__ bias,
                                                  __bf16* __restrict__ qb,
                                                  __bf16* __restrict__ kb,
                                                  __bf16* __restrict__ vtb) {
  __shared__ __align__(16) __bf16 lA[2*128*32];
  __shared__ __align__(16) __bf16 lB[2*128*32];
  f32x4 acc[4][4];
  #pragma unroll
  for (int i = 0; i < 4; ++i)
    #pragma unroll
    for (int j = 0; j < 4; ++j) { f32x4 z = {0.f,0.f,0.f,0.f}; acc[i][j] = z; }

  const int GX = N_QKV/128;  // 18
  int bid = blockIdx.y * GX + blockIdx.x;
  int cpx = (GX * ROWS/128) >> 3;
  int swz = (bid & 7) * cpx + (bid >> 3);
  const int m0 = (swz / GX) * 128, n0 = (swz % GX) * 128;
  gemm_core(xb, D_MODEL, wT, D_MODEL, D_MODEL, m0, n0, lA, lB, acc);

  const int lane = threadIdx.x & 63;
  const int wid  = threadIdx.x >> 6;
  const int wm = (wid >> 1) * 64, wn = (wid & 1) * 64;
  const int lr = lane & 15, lk = lane >> 4;
  #pragma unroll
  for (int mi = 0; mi < 4; ++mi) {
    #pragma unroll
    for (int ni = 0; ni < 4; ++ni) {
      int col = n0 + wn + ni*16 + lr;
      int t   = col / D_MODEL;
      int r2  = col - t*D_MODEL;
      int hh  = r2 >> 6, dk = r2 & 63;
      float bv = bias[col];
      #pragma unroll
      for (int j = 0; j < 4; ++j) {
        int row = m0 + wm + mi*16 + lk*4 + j;
        int bb = row >> 11, ss = row & 2047;
        float fv = acc[mi][ni][j] + bv;
        if (t == 0)      qb [(((size_t)bb*NH + hh)*SEQ + ss)*DKH + dk] = (__bf16)(fv * QSCALE);
        else if (t == 1) kb [(((size_t)bb*NH + hh)*SEQ + ss)*DKH + dk] = (__bf16)fv;
        else             vtb[(((size_t)bb*NH + hh)*DKH + dk)*SEQ + ss] = (__bf16)fv;
      }
    }
  }
}

// ---------------- GEMM3: out = attn @ WoutT + bout (fp32 out) ----------------
__global__ __launch_bounds__(256) void k_gemm_out(const __bf16* __restrict__ ab,
                                                  const __bf16* __restrict__ wT,
                                                  const float* __restrict__ bias,
                                                  float* __restrict__ out) {
  __shared__ __align__(16) __bf16 lA[2*128*32];
  __shared__ __align__(16) __bf16 lB[2*128*32];
  f32x4 acc[4][4];
  #pragma unroll
  for (int i = 0; i < 4; ++i)
    #pragma unroll
    for (int j = 0; j < 4; ++j) { f32x4 z = {0.f,0.f,0.f,0.f}; acc[i][j] = z; }

  const int GX = D_MODEL/128;  // 6
  int bid = blockIdx.y * GX + blockIdx.x;
  int cpx = (GX * ROWS/128) >> 3;
  int swz = (bid & 7) * cpx + (bid >> 3);
  const int m0 = (swz / GX) * 128, n0 = (swz % GX) * 128;
  gemm_core(ab, D_MODEL, wT, D_MODEL, D_MODEL, m0, n0, lA, lB, acc);

  const int lane = threadIdx.x & 63;
  const int wid  = threadIdx.x >> 6;
  const int wm = (wid >> 1) * 64, wn = (wid & 1) * 64;
  const int lr = lane & 15, lk = lane >> 4;
  #pragma unroll
  for (int mi = 0; mi < 4; ++mi) {
    #pragma unroll
    for (int ni = 0; ni < 4; ++ni) {
      int col = n0 + wn + ni*16 + lr;
      float bv = bias[col];
      #pragma unroll
      for (int j = 0; j < 4; ++j) {
        int row = m0 + wm + mi*16 + lk*4 + j;
        out[(size_t)row*D_MODEL + col] = acc[mi][ni][j] + bv;
      }
    }
  }
}

// Balanced qi map: three permutations of 0..15 with column sums 22/23 (per-CU
// causal work ~constant under round-robin block->CU assignment).
__device__ const int QI_TAB[3][16] = {
  { 0, 1, 2, 3, 4, 5, 6, 7, 8, 9,10,11,12,13,14,15},
  { 8, 9,10,11,12,13,14,15, 1, 2, 3, 4, 5, 6, 7, 0},
  {15,13,11, 9, 6, 4, 2, 0,14,12,10, 7, 5, 3, 1, 8}
};

// ---------------- Flash attention (causal), 8 waves x 16 q-rows ----------------
// grid (16, 48), 512 thr = 8 waves; block owns 128 q-rows (wave: 16), KVBLK=64.
// Same LDS/staging as R7 (K/V^T dbuf, swizzled; 1 K-load + 1 V-load per thread).
// Swapped QK^T (mfma(K,Q) -> S^T), in-lane softmax, in-register P -> PV under
// kv-permutation pi. Q pre-scaled (exp2 domain). setprio around MFMA clusters.
__global__ __launch_bounds__(512) void k_attn(const __bf16* __restrict__ q,
                                              const __bf16* __restrict__ k,
                                              const __bf16* __restrict__ vt,
                                              __bf16* __restrict__ out) {
  __shared__ __align__(16) char lsK[2][8192];   // [64 kv][64 d] bf16, swizzled rows
  __shared__ __align__(16) char lsV[2][8192];   // [64 d][64 kv] bf16, swizzled rows

  const int tid  = threadIdx.x;
  const int lane = tid & 63;
  const int wid  = tid >> 6;       // 0..7
  const int lr   = lane & 15;
  const int lk   = lane >> 4;

  const int bh = blockIdx.y;
  const int b  = bh / NH, h = bh - b*NH;
  const int qi  = QI_TAB[blockIdx.y >> 4][blockIdx.x];
  const int qb0 = qi * 128;
  const int q0w = qb0 + wid * 16;

  const __bf16* qh = q + (size_t)bh*SEQ*DKH;
  const char*   kB = (const char*)(k  + (size_t)bh*SEQ*DKH);
  const char*   vB = (const char*)(vt + (size_t)bh*DKH*SEQ);

  // Q fragments (B-operand of swapped QK): lane holds Q[q0w+lr][32c + 8lk .. +7]
  bf16x8 bq[2];
  #pragma unroll
  for (int c = 0; c < 2; ++c)
    bq[c] = *(const bf16x8*)(qh + (size_t)(q0w + lr)*DKH + c*32 + lk*8);

  // O accumulators: o[df]: rows q = q0w+4lk+j, col d = df*16+lr
  f32x4 o[4];
  #pragma unroll
  for (int df = 0; df < 4; ++df) { f32x4 z = {0.f,0.f,0.f,0.f}; o[df] = z; }
  // softmax state for q-row q0w + lr
  float m_i = -1e30f;
  float l_ln = 0.f;                 // per-lane partial row sum

  const int nt = qb0/64 + 2;        // kv tiles: [0, qb0+128)

  auto stage = [&](int buf, int kv0) {
    int lb   = wid*1024 + lane*16;                // linear dest byte in 8KB tile
    int row  = lb >> 7;                           // 128B rows
    int colb = (lb & 127) ^ ((row & 7) << 4);     // pre-swizzled source column
    __builtin_amdgcn_global_load_lds(
      (const __attribute__((address_space(1))) void*)(kB + (size_t)(kv0 + row)*128 + colb),
      (__attribute__((address_space(3))) void*)(lsK[buf] + wid*1024), 16, 0, 0);
    __builtin_amdgcn_global_load_lds(
      (const __attribute__((address_space(1))) void*)(vB + (size_t)row*(SEQ*2) + (size_t)kv0*2 + colb),
      (__attribute__((address_space(3))) void*)(lsV[buf] + wid*1024), 16, 0, 0);
  };

  stage(0, 0);
  __syncthreads();
  int cur = 0;

  for (int t = 0; t < nt; ++t) {
    const int kv0 = t * 64;
    if (t + 1 < nt) stage(cur ^ 1, kv0 + 64);

    if (kv0 <= q0w + 15) {          // wave-uniform causal activity
      // ---- S^T = K Q^T : C[kv][q]: lane q-col=lr, kv-row=16n+4lk+j ----
      f32x4 sc[4];
      #pragma unroll
      for (int n = 0; n < 4; ++n) { f32x4 z = {0.f,0.f,0.f,0.f}; sc[n] = z; }
      __builtin_amdgcn_s_setprio(1);
      #pragma unroll
      for (int n = 0; n < 4; ++n) {
        int kvl = n*16 + lr;
        const char* kr = lsK[cur] + kvl*128;
        int sw = (kvl & 7) << 4;
        bf16x8 ak0 = *(const bf16x8*)(kr + ((lk*16) ^ sw));       // K[kvl][8lk..], c=0
        bf16x8 ak1 = *(const bf16x8*)(kr + ((64 + lk*16) ^ sw));  // c=1
        sc[n] = __builtin_amdgcn_mfma_f32_16x16x32_bf16(ak0, bq[0], sc[n], 0, 0, 0);
        sc[n] = __builtin_amdgcn_mfma_f32_16x16x32_bf16(ak1, bq[1], sc[n], 0, 0, 0);
      }
      __builtin_amdgcn_s_setprio(0);
      // ---- causal mask (diag tiles only): kv = kv0+16n+4lk+j, q = q0w+lr ----
      if (kv0 + 63 > q0w) {
        int qrow = q0w + lr;
        #pragma unroll
        for (int n = 0; n < 4; ++n) {
          int kvb = kv0 + n*16 + lk*4;
          #pragma unroll
          for (int j = 0; j < 4; ++j)
            if (kvb + j > qrow) sc[n][j] = -1e30f;
        }
      }
      // ---- row max: in-lane over 16, then across lk groups (2 shuffles) ----
      float pm = sc[0][0];
      #pragma unroll
      for (int n = 0; n < 4; ++n)
        #pragma unroll
        for (int j = 0; j < 4; ++j)
          pm = fmaxf(pm, sc[n][j]);
      pm = fmaxf(pm, __shfl_xor(pm, 16));
      pm = fmaxf(pm, __shfl_xor(pm, 32));
      // ---- defer-max (T13) ----
      if (__any(pm > m_i + 8.0f)) {
        float mn = fmaxf(m_i, pm);
        float alpha = exp2f(m_i - mn);
        m_i = mn;
        l_ln *= alpha;
        // o rows are q=4lk+j: fetch alpha from lane lr'=4lk+j in own lk group
        #pragma unroll
        for (int j = 0; j < 4; ++j) {
          float av = __shfl(alpha, (lane & 48) | (lk*4 + j));
          #pragma unroll
          for (int df = 0; df < 4; ++df) o[df][j] *= av;
        }
      }
      // ---- P = exp2(s - m) in-register; build PV A-frags under kv-permutation pi ----
      float pv[4][4];
      #pragma unroll
      for (int n = 0; n < 4; ++n)
        #pragma unroll
        for (int j = 0; j < 4; ++j) {
          float e = exp2f(sc[n][j] - m_i);
          pv[n][j] = e;
          l_ln += e;
        }
      bf16x8 pa[2];
      #pragma unroll
      for (int c = 0; c < 2; ++c)
        #pragma unroll
        for (int t2 = 0; t2 < 8; ++t2)
          pa[c][t2] = (__bf16)pv[2*c + (t2>>2)][t2 & 3];
      // ---- O += P V with V read under pi ----
      __builtin_amdgcn_s_setprio(1);
      #pragma unroll
      for (int df = 0; df < 4; ++df) {
        int d = df*16 + lr;
        const char* vr = lsV[cur] + d*128;
        int sw = (d & 7) << 4;
        #pragma unroll
        for (int c = 0; c < 2; ++c) {
          bf16x4 v0 = *(const bf16x4*)(vr + ((c*64 + lk*8) ^ sw));
          bf16x4 v1 = *(const bf16x4*)(vr + ((c*64 + 32 + lk*8) ^ sw));
          bf16x8 bv = {v0[0], v0[1], v0[2], v0[3], v1[0], v1[1], v1[2], v1[3]};
          o[df] = __builtin_amdgcn_mfma_f32_16x16x32_bf16(pa[c], bv, o[df], 0, 0, 0);
        }
      }
      __builtin_amdgcn_s_setprio(0);
    }
    __syncthreads();
    cur ^= 1;
  }

  // ---- epilogue: reduce l across lk groups, invert, redistribute, store ----
  float v = l_ln;
  v += __shfl_xor(v, 16);
  v += __shfl_xor(v, 32);
  float inv = 1.0f / v;
  float iv[4];
  #pragma unroll
  for (int j = 0; j < 4; ++j)
    iv[j] = __shfl(inv, (lane & 48) | (lk*4 + j));
  #pragma unroll
  for (int df = 0; df < 4; ++df) {
    int d = df*16 + lr;
    #pragma unroll
    for (int j = 0; j < 4; ++j) {
      int ss = q0w + lk*4 + j;
      out[((size_t)b*SEQ + ss)*D_MODEL + h*DKH + d] = (__bf16)(o[df][j] * iv[j]);
    }
  }
}

// ---------------- launch ----------------
extern "C" void kernel_launch(void* const* d_in, const int* in_sizes, int n_in,
                              void* d_out, int out_size, void* d_ws, size_t ws_size,
                              hipStream_t stream) {
  const float* x    = (const float*)d_in[0];
  /* d_in[1] = causal mask, implemented analytically */
  const float* Wqkv = (const float*)d_in[2];
  const float* bqkv = (const float*)d_in[3];
  const float* Wout = (const float*)d_in[4];
  const float* bout = (const float*)d_in[5];
  float* out = (float*)d_out;

  char* w = (char*)d_ws;
  __bf16* xb    = (__bf16*)w; w += (size_t)ROWS*D_MODEL*2;
  __bf16* wqkvT = (__bf16*)w; w += (size_t)N_QKV*D_MODEL*2;
  __bf16* woutT = (__bf16*)w; w += (size_t)D_MODEL*D_MODEL*2;
  __bf16* qb    = (__bf16*)w; w += (size_t)BATCH*NH*SEQ*DKH*2;
  __bf16* kb    = (__bf16*)w; w += (size_t)BATCH*NH*SEQ*DKH*2;
  __bf16* vtb   = (__bf16*)w; w += (size_t)BATCH*NH*SEQ*DKH*2;
  __bf16* attnb = (__bf16*)w; w += (size_t)ROWS*D_MODEL*2;

  k_convert<<<(ROWS*D_MODEL/4 + 255)/256, 256, 0, stream>>>(x, xb, ROWS*D_MODEL);
  k_transpose<<<dim3(N_QKV/32, D_MODEL/32), dim3(32, 8), 0, stream>>>(Wqkv, wqkvT, D_MODEL, N_QKV);
  k_transpose<<<dim3(D_MODEL/32, D_MODEL/32), dim3(32, 8), 0, stream>>>(Wout, woutT, D_MODEL, D_MODEL);
  k_gemm_qkv<<<dim3(N_QKV/128, ROWS/128), 256, 0, stream>>>(xb, wqkvT, bqkv, qb, kb, vtb);
  k_attn<<<dim3(16, BATCH*NH), 512, 0, stream>>>(qb, kb, vtb, attnb);
  k_gemm_out<<<dim3(D_MODEL/128, ROWS/128), 256, 0, stream>>>(attnb, woutT, bout, out);
}